// Round 9
// baseline (293.365 us; speedup 1.0000x reference)
//
#include <hip/hip_runtime.h>
#include <hip/hip_bf16.h>
#include <hip/hip_cooperative_groups.h>

namespace cg = cooperative_groups;

// B=8, H=64, W=64, C=256, NUM_HEADS=8, dph=32, DIL=3, k2=9
// Single cooperative kernel, 3 phases with grid.sync():
//   A: convert x,W f32->bf16 (XCD-aligned: XCD x converts batch x)
//   B: qkv GEMM Y[32768,768] = xb @ wb^T, 128x128 tiles (XCD x owns batch x rows)
//   C: dilated attention (XCD x owns batch x pixels)
// ws layout (ushort units): xb[8388608] | wb[196608] | qkv[25165824]

typedef unsigned short ushortT;
typedef __attribute__((ext_vector_type(8))) short short8;
typedef __attribute__((ext_vector_type(4))) float f32x4;

__device__ __forceinline__ ushortT f2b(float f) {  // RTNE f32 -> bf16 bits
    unsigned u = __float_as_uint(f);
    return (ushortT)((u + 0x7fffu + ((u >> 16) & 1u)) >> 16);
}
__device__ __forceinline__ float b2f(ushortT u) {
    return __uint_as_float((unsigned)u << 16);
}

__global__ __launch_bounds__(256, 5) void fused(const float* __restrict__ x,
                                                const float* __restrict__ Wq,
                                                float* __restrict__ out,
                                                ushortT* __restrict__ xb,
                                                ushortT* __restrict__ wb,
                                                ushortT* __restrict__ qkv) {
    __shared__ __align__(16) ushortT smem[16384];  // 32KB (GEMM staging + epilogue)

    const int t = threadIdx.x;
    const int bid = blockIdx.x;
    const int nbpx = gridDim.x >> 3;   // blocks per XCD
    const int xcd = bid & 7, local = bid >> 3;

    // ---------------- Phase A: f32 -> bf16 ----------------
    // x: XCD x converts its batch: float4 indices [xcd*262144, (xcd+1)*262144)
    for (int j = local * 256 + t; j < 262144; j += nbpx * 256) {
        int i = xcd * 262144 + j;
        float4 f = ((const float4*)x)[i];
        ushort4 u = {f2b(f.x), f2b(f.y), f2b(f.z), f2b(f.w)};
        ((ushort4*)xb)[i] = u;
    }
    // W: global stripe (tiny, 49152 float4s)
    for (int j = bid * 256 + t; j < 49152; j += gridDim.x * 256) {
        float4 f = ((const float4*)Wq)[j];
        ushort4 u = {f2b(f.x), f2b(f.y), f2b(f.z), f2b(f.w)};
        ((ushort4*)wb)[j] = u;
    }

    __threadfence();
    cg::this_grid().sync();

    // ---------------- Phase B: bf16 MFMA GEMM ----------------
    // 192 tiles per XCD (mblk in [xcd*32,(xcd+1)*32), nblk 0..5), grid-strided.
    const int lane = t & 63, wv = t >> 6;
    const int wm = (wv >> 1) * 64, wn = (wv & 1) * 64;
    const int lr = lane & 15, g = lane >> 4;
    const int srow = t >> 3, sslot = t & 7;
    const int wvbase = (t & ~63) * 8;

    for (int tk = local; tk < 192; tk += nbpx) {
        int swz = xcd * 192 + tk;
        int mblk = swz / 6, nblk = swz - mblk * 6;
        const int m0 = mblk * 128, n0 = nblk * 128;

        ushortT* As = smem;
        ushortT* Bs = smem + 8192;
        f32x4 acc[4][4] = {};

        for (int k0 = 0; k0 < 256; k0 += 64) {
            __syncthreads();
#pragma unroll
            for (int r = 0; r < 4; ++r) {
                int row = r * 32 + srow;
                int ss = sslot ^ (row & 7);
                const ushortT* ga = xb + (size_t)(m0 + row) * 256 + k0 + ss * 8;
                const ushortT* gb = wb + (size_t)(n0 + row) * 256 + k0 + ss * 8;
                __builtin_amdgcn_global_load_lds(
                    (const __attribute__((address_space(1))) unsigned int*)ga,
                    (__attribute__((address_space(3))) unsigned int*)(As + r * 2048 + wvbase),
                    16, 0, 0);
                __builtin_amdgcn_global_load_lds(
                    (const __attribute__((address_space(1))) unsigned int*)gb,
                    (__attribute__((address_space(3))) unsigned int*)(Bs + r * 2048 + wvbase),
                    16, 0, 0);
            }
            __syncthreads();  // compiler drains vmcnt before barrier

#pragma unroll
            for (int ksub = 0; ksub < 2; ++ksub) {
                short8 af[4], bfr[4];
#pragma unroll
                for (int mi = 0; mi < 4; ++mi) {
                    int row = wm + mi * 16 + lr;
                    int slot = (ksub * 4 + g) ^ (row & 7);
                    af[mi] = *(const short8*)&As[row * 64 + slot * 8];
                }
#pragma unroll
                for (int ni = 0; ni < 4; ++ni) {
                    int row = wn + ni * 16 + lr;
                    int slot = (ksub * 4 + g) ^ (row & 7);
                    bfr[ni] = *(const short8*)&Bs[row * 64 + slot * 8];
                }
#pragma unroll
                for (int mi = 0; mi < 4; ++mi)
#pragma unroll
                    for (int ni = 0; ni < 4; ++ni)
                        acc[mi][ni] = __builtin_amdgcn_mfma_f32_16x16x32_bf16(
                            af[mi], bfr[ni], acc[mi][ni], 0, 0, 0);
            }
        }

        // epilogue: acc -> LDS (bf16, swizzled) -> coalesced 16B stores
        __syncthreads();
        // C/D layout: col = lane&15, row = (lane>>4)*4 + reg
#pragma unroll
        for (int mi = 0; mi < 4; ++mi)
#pragma unroll
            for (int ni = 0; ni < 4; ++ni) {
                int col = wn + ni * 16 + lr;
#pragma unroll
                for (int rg = 0; rg < 4; ++rg) {
                    int row = wm + mi * 16 + g * 4 + rg;
                    int sc = col ^ (((row >> 2) & 3) << 4);
                    smem[row * 128 + sc] = f2b(acc[mi][ni][rg]);
                }
            }
        __syncthreads();
#pragma unroll
        for (int p = 0; p < 8; ++p) {
            int cid = p * 256 + t;          // 0..2047
            int row = cid >> 4;             // 0..127
            int c0 = (cid & 15) * 8;        // 0..120
            int sc0 = c0 ^ (((row >> 2) & 3) << 4);
            short8 vv = *(const short8*)&smem[row * 128 + sc0];
            *(short8*)&qkv[(size_t)(m0 + row) * 768 + n0 + c0] = vv;
        }
    }

    __threadfence();
    cg::this_grid().sync();

    // ---------------- Phase C: dilated attention ----------------
    // 2048 wave-pairs per XCD (each wave = 2 pixels of batch xcd).
    const float scale = 0.17677669529663689f;  // 1/sqrt(32)
    const int half = (t >> 5) & 1;
    const int l = t & 31;

    for (int k = local * 4 + wv; k < 2048; k += nbpx * 4) {
        const int wid = (xcd * 2048 + k) * 2 + half;  // pixel
        const int b = wid >> 12, pix = wid & 4095;
        const int h = pix >> 6, w = pix & 63;

        const size_t pbase = (size_t)wid * 768;
        short8 qu = *(const short8*)&qkv[pbase + l * 8];
        float q[8];
#pragma unroll
        for (int c = 0; c < 8; ++c) q[c] = b2f((ushortT)qu[c]) * scale;

        float s[9];
        short8 vu[9];
#pragma unroll
        for (int i = 0; i < 3; ++i) {
#pragma unroll
            for (int j = 0; j < 3; ++j) {
                const int kk = i * 3 + j;
                const int hh = h + (i - 1) * 3;
                const int ww = w + (j - 1) * 3;
                float p = 0.f;
                short8 z = {0, 0, 0, 0, 0, 0, 0, 0};
                vu[kk] = z;
                if ((unsigned)hh < 64u && (unsigned)ww < 64u) {
                    const size_t nb2 = ((size_t)((b << 12) + (hh << 6) + ww)) * 768;
                    short8 ku = *(const short8*)&qkv[nb2 + 256 + l * 8];
                    vu[kk] = *(const short8*)&qkv[nb2 + 512 + l * 8];
#pragma unroll
                    for (int c = 0; c < 8; ++c) p = fmaf(q[c], b2f((ushortT)ku[c]), p);
                }
                p += __shfl_xor(p, 1);
                p += __shfl_xor(p, 2);  // 4-lane (one head) reduce
                s[kk] = p;
            }
        }

        float m = s[0];
#pragma unroll
        for (int kk = 1; kk < 9; ++kk) m = fmaxf(m, s[kk]);
        float denom = 0.f;
        float o[8] = {};
#pragma unroll
        for (int kk = 0; kk < 9; ++kk) {
            float e = __expf(s[kk] - m);
            denom += e;
#pragma unroll
            for (int c = 0; c < 8; ++c) o[c] = fmaf(e, b2f((ushortT)vu[kk][c]), o[c]);
        }
        const float inv = 1.0f / denom;
        float* op = &out[(size_t)wid * 256 + l * 8];
        float4 o0 = make_float4(o[0] * inv, o[1] * inv, o[2] * inv, o[3] * inv);
        float4 o1 = make_float4(o[4] * inv, o[5] * inv, o[6] * inv, o[7] * inv);
        *(float4*)op = o0;
        *(float4*)(op + 4) = o1;
    }
}

extern "C" void kernel_launch(void* const* d_in, const int* in_sizes, int n_in,
                              void* d_out, int out_size, void* d_ws, size_t ws_size,
                              hipStream_t stream) {
    const float* x  = (const float*)d_in[0];   // [8,64,64,256] f32
    const float* Wq = (const float*)d_in[1];   // [768,256] f32
    float* out = (float*)d_out;                // [8,64,64,256] f32

    ushortT* xb  = (ushortT*)d_ws;             // [32768,256] bf16
    ushortT* wb  = xb + (size_t)8388608;       // [768,256]  bf16
    ushortT* qkv = wb + (size_t)196608;        // [32768,768] bf16

    int nb = 0;
    hipOccupancyMaxActiveBlocksPerMultiprocessor(&nb, (const void*)fused, 256, 0);
    if (nb > 5) nb = 5;   // LDS bound: 5 x 32KB = 160KB/CU
    if (nb < 1) nb = 1;
    dim3 grid(nb * 256);

    void* args[] = {(void*)&x, (void*)&Wq, (void*)&out,
                    (void*)&xb, (void*)&wb, (void*)&qkv};
    hipLaunchCooperativeKernel((const void*)fused, grid, dim3(256), args, 0, stream);
}

// Round 10
// 52.141 us; speedup vs baseline: 5.6264x; 5.6264x over previous
//
#include <hip/hip_runtime.h>
#include <hip/hip_bf16.h>

// B=8, H=64, W=64, C=256, NUM_HEADS=8, dph=32, DIL=3, k2=9
// qkv GEMM: Y[32768,768] = X[32768,256] @ W[768,256]^T in bf16 MFMA.
// ws layout (ushort units): xb[8388608] | wb[196608] | qkv[25165824]  (67.5 MB)
// Structure locked per rounds 3-9: to_bf16 -> m97-pattern GEMM -> attn3.

typedef unsigned short ushortT;
typedef __attribute__((ext_vector_type(8))) short short8;
typedef __attribute__((ext_vector_type(4))) float f32x4;

__device__ __forceinline__ ushortT f2b(float f) {  // RTNE f32 -> bf16 bits
    unsigned u = __float_as_uint(f);
    return (ushortT)((u + 0x7fffu + ((u >> 16) & 1u)) >> 16);
}
__device__ __forceinline__ float b2f(ushortT u) {
    return __uint_as_float((unsigned)u << 16);
}

// ---- convert x [8388608 f32] and W [196608 f32] to bf16; grid-stride, 2048 blocks ----
__global__ __launch_bounds__(256) void to_bf16(const float* __restrict__ x,
                                               const float* __restrict__ wq,
                                               ushortT* __restrict__ xb,
                                               ushortT* __restrict__ wb) {
    const int N4X = 2097152, N4T = 2097152 + 49152;
    for (int i = blockIdx.x * 256 + threadIdx.x; i < N4T; i += 2048 * 256) {
        if (i < N4X) {
            float4 f = ((const float4*)x)[i];
            ushort4 u = {f2b(f.x), f2b(f.y), f2b(f.z), f2b(f.w)};
            ((ushort4*)xb)[i] = u;
        } else {
            int j = i - N4X;
            float4 f = ((const float4*)wq)[j];
            ushort4 u = {f2b(f.x), f2b(f.y), f2b(f.z), f2b(f.w)};
            ((ushort4*)wb)[j] = u;
        }
    }
}

// ---- bf16 MFMA GEMM: 128x128 tile, BK=64, 4 waves (2x2), 16x16x32 MFMA ----
// Staging via global_load_lds (16B), XOR slot-swizzle carried on the global
// source address (G21: linear LDS dest + inverse-swizzled source + swizzled read).
// Epilogue: repack C through the same 32KB LDS -> coalesced 16B stores.
__global__ __launch_bounds__(256) void gemm_qkv(const ushortT* __restrict__ A,
                                                const ushortT* __restrict__ Bw,
                                                ushortT* __restrict__ Y) {
    __shared__ __align__(16) ushortT smem[16384];  // As[0:8192) Bs[8192:16384); epilogue 128x128
    ushortT* As = smem;
    ushortT* Bs = smem + 8192;

    // XCD-chunked swizzle: 1536 blocks, 8 XCDs, 192 per XCD (bijective).
    int bid = blockIdx.x;
    int swz = (bid & 7) * 192 + (bid >> 3);
    int mblk = swz / 6, nblk = swz - mblk * 6;
    const int m0 = mblk * 128, n0 = nblk * 128;

    const int t = threadIdx.x;
    const int lane = t & 63, wv = t >> 6;
    const int wm = (wv >> 1) * 64, wn = (wv & 1) * 64;
    const int lr = lane & 15, g = lane >> 4;
    const int srow = t >> 3, sslot = t & 7;      // staging: row within 32-row strip, 16B slot
    const int wvbase = (t & ~63) * 8;            // wave-uniform LDS base (ushort): wv*512

    f32x4 acc[4][4] = {};

    for (int k0 = 0; k0 < 256; k0 += 64) {
        __syncthreads();
#pragma unroll
        for (int r = 0; r < 4; ++r) {
            int row = r * 32 + srow;
            int ss = sslot ^ (row & 7);
            const ushortT* ga = A + (size_t)(m0 + row) * 256 + k0 + ss * 8;
            const ushortT* gb = Bw + (size_t)(n0 + row) * 256 + k0 + ss * 8;
            __builtin_amdgcn_global_load_lds(
                (const __attribute__((address_space(1))) unsigned int*)ga,
                (__attribute__((address_space(3))) unsigned int*)(As + r * 2048 + wvbase),
                16, 0, 0);
            __builtin_amdgcn_global_load_lds(
                (const __attribute__((address_space(1))) unsigned int*)gb,
                (__attribute__((address_space(3))) unsigned int*)(Bs + r * 2048 + wvbase),
                16, 0, 0);
        }
        __syncthreads();  // compiler drains vmcnt before barrier

#pragma unroll
        for (int ksub = 0; ksub < 2; ++ksub) {
            short8 af[4], bfr[4];
#pragma unroll
            for (int mi = 0; mi < 4; ++mi) {
                int row = wm + mi * 16 + lr;
                int slot = (ksub * 4 + g) ^ (row & 7);
                af[mi] = *(const short8*)&As[row * 64 + slot * 8];
            }
#pragma unroll
            for (int ni = 0; ni < 4; ++ni) {
                int row = wn + ni * 16 + lr;
                int slot = (ksub * 4 + g) ^ (row & 7);
                bfr[ni] = *(const short8*)&Bs[row * 64 + slot * 8];
            }
#pragma unroll
            for (int mi = 0; mi < 4; ++mi)
#pragma unroll
                for (int ni = 0; ni < 4; ++ni)
                    acc[mi][ni] = __builtin_amdgcn_mfma_f32_16x16x32_bf16(
                        af[mi], bfr[ni], acc[mi][ni], 0, 0, 0);
        }
    }

    // ---- epilogue: acc -> LDS (bf16, swizzled) -> coalesced 16B stores ----
    __syncthreads();  // all ds_reads of As/Bs complete before overwrite
    // C/D layout: col = lane&15, row = (lane>>4)*4 + reg
#pragma unroll
    for (int mi = 0; mi < 4; ++mi)
#pragma unroll
        for (int ni = 0; ni < 4; ++ni) {
            int col = wn + ni * 16 + lr;
#pragma unroll
            for (int rg = 0; rg < 4; ++rg) {
                int row = wm + mi * 16 + g * 4 + rg;
                int sc = col ^ (((row >> 2) & 3) << 4);
                smem[row * 128 + sc] = f2b(acc[mi][ni][rg]);
            }
        }
    __syncthreads();
#pragma unroll
    for (int p = 0; p < 8; ++p) {
        int cid = p * 256 + t;          // 0..2047
        int row = cid >> 4;             // 0..127
        int c0 = (cid & 15) * 8;        // 0..120
        int sc0 = c0 ^ (((row >> 2) & 3) << 4);
        short8 vv = *(const short8*)&smem[row * 128 + sc0];
        *(short8*)&Y[(size_t)(m0 + row) * 768 + n0 + c0] = vv;
    }
}

// ---- attention: 2 pixels per wave; lane owns 8 channels (head = (lane&31)>>2) ----
// Dot-reduce = 2 shfl_xor within 4-lane group. Softmax in exp2 domain:
// q pre-scaled by scale*log2(e); OOB logits are exactly 0 in both domains.
__global__ __launch_bounds__(256) void attn3(const ushortT* __restrict__ qkv,
                                             float* __restrict__ out) {
    const float scale2 = 0.17677669529663689f * 1.4426950408889634f;  // 1/sqrt(32)*log2(e)
    int bid = blockIdx.x;
    int sbid = (bid & 7) * 512 + (bid >> 3);   // XCD-chunk swizzle (bijective)
    const int t = threadIdx.x;
    const int wpair = sbid * 4 + (t >> 6);     // 0..16383
    const int half = (t >> 5) & 1;
    const int l = t & 31;                      // lane within pixel
    const int wid = wpair * 2 + half;          // pixel 0..32767
    const int b = wid >> 12, pix = wid & 4095;
    const int h = pix >> 6, w = pix & 63;

    const size_t pbase = (size_t)wid * 768;
    short8 qu = *(const short8*)&qkv[pbase + l * 8];
    float q[8];
#pragma unroll
    for (int c = 0; c < 8; ++c) q[c] = b2f((ushortT)qu[c]) * scale2;

    float s[9];
    short8 vu[9];
#pragma unroll
    for (int i = 0; i < 3; ++i) {
#pragma unroll
        for (int j = 0; j < 3; ++j) {
            const int kk = i * 3 + j;
            const int hh = h + (i - 1) * 3;
            const int ww = w + (j - 1) * 3;
            float p = 0.f;
            short8 z = {0, 0, 0, 0, 0, 0, 0, 0};
            vu[kk] = z;
            if ((unsigned)hh < 64u && (unsigned)ww < 64u) {
                const size_t nb = ((size_t)((b << 12) + (hh << 6) + ww)) * 768;
                short8 ku = *(const short8*)&qkv[nb + 256 + l * 8];
                vu[kk] = *(const short8*)&qkv[nb + 512 + l * 8];
#pragma unroll
                for (int c = 0; c < 8; ++c) p = fmaf(q[c], b2f((ushortT)ku[c]), p);
            }
            p += __shfl_xor(p, 1);
            p += __shfl_xor(p, 2);  // 4-lane (one head) reduce
            s[kk] = p;
        }
    }

    float m = s[0];
#pragma unroll
    for (int kk = 1; kk < 9; ++kk) m = fmaxf(m, s[kk]);
    float denom = 0.f;
    float o[8] = {};
#pragma unroll
    for (int kk = 0; kk < 9; ++kk) {
        float e = exp2f(s[kk] - m);  // softmax shift-invariant in log2 domain
        denom += e;
#pragma unroll
        for (int c = 0; c < 8; ++c) o[c] = fmaf(e, b2f((ushortT)vu[kk][c]), o[c]);
    }
    const float inv = 1.0f / denom;
    float* op = &out[(size_t)wid * 256 + l * 8];
    float4 o0 = make_float4(o[0] * inv, o[1] * inv, o[2] * inv, o[3] * inv);
    float4 o1 = make_float4(o[4] * inv, o[5] * inv, o[6] * inv, o[7] * inv);
    *(float4*)op = o0;
    *(float4*)(op + 4) = o1;
}

extern "C" void kernel_launch(void* const* d_in, const int* in_sizes, int n_in,
                              void* d_out, int out_size, void* d_ws, size_t ws_size,
                              hipStream_t stream) {
    const float* x  = (const float*)d_in[0];   // [8,64,64,256]
    const float* Wq = (const float*)d_in[1];   // [768,256]
    float* out = (float*)d_out;                // [8,64,64,256]

    ushortT* xb  = (ushortT*)d_ws;             // [32768,256] bf16
    ushortT* wb  = xb + (size_t)8388608;       // [768,256]  bf16
    ushortT* qkv = wb + (size_t)196608;        // [32768,768] bf16

    to_bf16<<<2048, 256, 0, stream>>>(x, Wq, xb, wb);
    gemm_qkv<<<1536, 256, 0, stream>>>(xb, wb, qkv);
    attn3<<<4096, 256, 0, stream>>>(qkv, out);
}